// Round 12
// baseline (2181.459 us; speedup 1.0000x reference)
//
#include <hip/hip_runtime.h>
#include <hip/hip_bf16.h>
#include <cstdint>

#define BATCH   4096
#define IN_DIM  1024
#define OUT_DIM 1024
#define NEXP    16

typedef __bf16 bf16;
typedef __attribute__((ext_vector_type(8))) __bf16 bf16x8;
typedef __attribute__((ext_vector_type(4))) float  f32x4;

#define AS1 __attribute__((address_space(1)))
#define AS3 __attribute__((address_space(3)))

// ---------------------------------------------------------------------------
// Merged conversion kernel (unchanged — proven clean).
// Blocks [0,4096): weight fp32 -> fragment-ordered bf16 tiles via LDS
//   transpose (coalesced f32x4 row reads).
// Blocks [4096,4608): x fp32 -> 512 pre-tiled swizzled bf16 images.
// ---------------------------------------------------------------------------
__global__ __launch_bounds__(256) void convert_all(
        const float* __restrict__ x, const float* __restrict__ W,
        bf16* __restrict__ xt, bf16* __restrict__ wt) {
    __shared__ float Ls[64][65];       // pad 65: read phase is 2-way (free)
    int t = threadIdx.x;
    int bid = blockIdx.x;
    if (bid < 4096) {
        int nblk = bid >> 8, ne = (bid >> 4) & 15, ks = bid & 15;
        int kb = ne * 1024 + ks * 64;
        int n0 = nblk * 64;
#pragma unroll
        for (int r = 0; r < 4; r++) {
            int idx = r * 256 + t;             // 1024 f32x4 = 64x64 tile
            int row = idx >> 4, c4 = (idx & 15) * 4;
            f32x4 v = *(const f32x4*)(W + (size_t)(kb + row) * OUT_DIM + n0 + c4);
#pragma unroll
            for (int j = 0; j < 4; j++) Ls[row][c4 + j] = v[j];
        }
        __syncthreads();
#pragma unroll
        for (int r = 0; r < 2; r++) {
            int c = r * 256 + t;               // 0..511
            int sub = c >> 6, l = c & 63;
            int lr = l & 15, lq = l >> 4;
            int kk = sub >> 2, wn = (sub >> 1) & 1, nt = sub & 1;
            int krow = kk * 32 + lq * 8;
            int col = wn * 32 + nt * 16 + lr;
            bf16x8 v;
#pragma unroll
            for (int j = 0; j < 8; j++) v[j] = (bf16)Ls[krow + j][col];
            *(bf16x8*)(wt + (size_t)bid * 4096 + c * 8) = v;
        }
    } else {
        int tile = bid - 4096;                 // 512
        int mblk = tile >> 4, ks = tile & 15;
#pragma unroll
        for (int r = 0; r < 4; r++) {
            int q = r * 256 + t;
            int m_loc = q >> 3, sc = q & 7;
            int cc = sc ^ (m_loc & 7);
            const float* src = x + (size_t)(mblk * 128 + m_loc) * IN_DIM + ks * 64 + cc * 8;
            f32x4 a = *(const f32x4*)src;
            f32x4 b = *(const f32x4*)(src + 4);
            bf16x8 v;
#pragma unroll
            for (int j = 0; j < 4; j++) { v[j] = (bf16)a[j]; v[4 + j] = (bf16)b[j]; }
            *(bf16x8*)(xt + (size_t)tile * 8192 + q * 8) = v;
        }
    }
}

// ---------------------------------------------------------------------------
// GEMM R12: barrier-free register streaming (R11) + REGISTER DOUBLE-BUFFERED
// B PREFETCH, distance 1 expert.
// Evidence: R11 (no barriers, no LDS operands) still 38% MfmaUtil / 155us —
// same as every barrier variant. Invariant cause: per expert(-group) the
// wave issues loads, waits, THEN MFMAs; nothing pipelines across the
// boundary (the unroll-1 spill guard forbade hoisting). Fix: two named
// fragment buffers bA/bB alternated at COMPILE-TIME parity over a fully
// unrolled 16-expert loop; at expert e, issue the 4 dwordx4 loads of e+1
// (or (ks+1,0) at e==15) into the other buffer, then MFMA from the current
// one. Compiler emits counted vmcnt automatically (4 newer loads in
// flight) — the T4 effect with zero inline asm. In-flight loads bounded at
// 8; all register indices compile-time (rule #20).
// Transposed compute (R5/R7-verified): p = mfma(B,A) -> D=(xW)^T; scale =
// per-lane scalar from LDS cwS (global scales spilled in R10).
// Block 128m x 64n, 4 waves (2x2), wave tile 64x32, mfma 16x16x32 bf16.
// LDS 10.3 KB (cwS only); grid 512 = 2 blocks/CU; both blocks on a CU
// share nblk -> B fragments are L1-resident after first touch.
// ---------------------------------------------------------------------------

// load the 4 B fragments of tile TILEOFF (in 4096-elem units) into BUF
#define BLOAD(BUF, TILEOFF) do {                                               \
    const bf16* bt_ = bbase + (size_t)(TILEOFF) * 4096;                        \
    BUF[0][0] = *(const bf16x8*)(bt_ + ((0 * 2 + wn) * 2 + 0) * 512);          \
    BUF[0][1] = *(const bf16x8*)(bt_ + ((0 * 2 + wn) * 2 + 1) * 512);          \
    BUF[1][0] = *(const bf16x8*)(bt_ + ((1 * 2 + wn) * 2 + 0) * 512);          \
    BUF[1][1] = *(const bf16x8*)(bt_ + ((1 * 2 + wn) * 2 + 1) * 512);          \
} while (0)

// one expert step: prefetch e+1 into NXT, compute e from CUR
#define STEPE(E, CUR, NXT) do {                                                \
    if ((E) < 15) BLOAD(NXT, ((E) + 1) * 16 + ks);                             \
    else if (ks < 15) BLOAD(NXT, ks + 1);           /* (ks+1, ne=0) */         \
    if (((E) & 3) == 0) {                                                      \
        _Pragma("unroll")                                                      \
        for (int mt = 0; mt < 4; mt++)                                         \
            sg[mt] = *(const f32x4*)(cwrow0 + mt * (16 * 20) + ((E) >> 2) * 4);\
    }                                                                          \
    _Pragma("unroll")                                                          \
    for (int mt = 0; mt < 4; mt++) {                                           \
        float sv = sg[mt][(E) & 3];                                            \
        _Pragma("unroll")                                                      \
        for (int nt = 0; nt < 2; nt++) {                                       \
            f32x4 p = __builtin_amdgcn_mfma_f32_16x16x32_bf16(                 \
                CUR[0][nt], af[mt][0], fz, 0, 0, 0);                           \
            p = __builtin_amdgcn_mfma_f32_16x16x32_bf16(                       \
                CUR[1][nt], af[mt][1], p, 0, 0, 0);                            \
            acc[mt][nt] += sv * p;                                             \
        }                                                                      \
    }                                                                          \
} while (0)

__global__ __launch_bounds__(256, 2) void moe_gemm(
        const float* __restrict__ cw, const float* __restrict__ bias,
        const bf16* __restrict__ xt, const bf16* __restrict__ wt,
        float* __restrict__ out) {
    int nblk = blockIdx.x;                 // 16; x-major dispatch -> bid%8 =
    int mblk = blockIdx.y;                 // nblk%8 clusters nblk per XCD
    int m0 = mblk * 128, n0 = nblk * 64;
    int t = threadIdx.x;
    int lane = t & 63, w = t >> 6;
    int wm = w >> 1, wn = w & 1;
    int lq = lane >> 4, lr = lane & 15;

    __shared__ float cwS[128][20];         // cwS[row_loc][ne], pad 20

    // fill scale table: coalesced f32x4 global loads, aligned b128 LDS writes
#pragma unroll
    for (int r = 0; r < 2; r++) {
        int q = r * 256 + t;               // 512 f32x4 = 2048 floats
        f32x4 v = *(const f32x4*)(cw + (size_t)m0 * NEXP + q * 4);
        *(f32x4*)&cwS[q >> 2][(q & 3) * 4] = v;
    }
    __syncthreads();                       // the ONLY barrier

    const f32x4 fz = {0.f, 0.f, 0.f, 0.f};
    f32x4 acc[4][2];
#pragma unroll
    for (int mt = 0; mt < 4; mt++)
#pragma unroll
        for (int nt = 0; nt < 2; nt++) acc[mt][nt] = fz;

    int swz = lr & 7;
    int mrow[4];
#pragma unroll
    for (int mt = 0; mt < 4; mt++) mrow[mt] = (wm * 64 + mt * 16 + lr) * 64;

    const bf16* abase = xt + (size_t)(mblk * 16) * 8192;
    const bf16* bbase = wt + (size_t)nblk * (16 * 16 * 4096) + lane * 8;
    const float* cwrow0 = &cwS[wm * 64 + lr][0];

    bf16x8 bA[2][2], bB[2][2];             // double-buffered B fragments
    BLOAD(bA, 0);                          // prologue: tile (ks=0, ne=0)

    f32x4 sg[4];                           // 4-expert scale group

#pragma unroll 1
    for (int ks = 0; ks < 16; ks++) {
        // A fragments -> registers straight from the xt image (L1/L2-hot),
        // reused across all 16 experts
        bf16x8 af[4][2];
        const bf16* asrc = abase + (size_t)ks * 8192;
#pragma unroll
        for (int kk = 0; kk < 2; kk++)
#pragma unroll
            for (int mt = 0; mt < 4; mt++)
                af[mt][kk] = *(const bf16x8*)
                    (asrc + mrow[mt] + ((kk * 4 + lq) ^ swz) * 8);

        // 16 experts, compile-time parity double-buffer: even e from bA,
        // odd e from bB; prefetch e+1 into the other buffer.
        STEPE(0,  bA, bB); STEPE(1,  bB, bA);
        STEPE(2,  bA, bB); STEPE(3,  bB, bA);
        STEPE(4,  bA, bB); STEPE(5,  bB, bA);
        STEPE(6,  bA, bB); STEPE(7,  bB, bA);
        STEPE(8,  bA, bB); STEPE(9,  bB, bA);
        STEPE(10, bA, bB); STEPE(11, bB, bA);
        STEPE(12, bA, bB); STEPE(13, bB, bA);
        STEPE(14, bA, bB); STEPE(15, bB, bA);
    }

    // ---- bias: one MFMA k-step (k = ne), swapped operands like the body ----
    {
        bf16x8 acw[4];
#pragma unroll
        for (int mt = 0; mt < 4; mt++) {
            bf16x8 v;
#pragma unroll
            for (int j = 0; j < 8; j++) v[j] = (bf16)0.f;
            if (lq < 2) {                  // k = lq*8+j in 0..15 real, else 0
                int row = m0 + wm * 64 + mt * 16 + lr;
                f32x4 a = *(const f32x4*)(cw + (size_t)row * NEXP + lq * 8);
                f32x4 b = *(const f32x4*)(cw + (size_t)row * NEXP + lq * 8 + 4);
#pragma unroll
                for (int j = 0; j < 4; j++) { v[j] = (bf16)a[j]; v[4 + j] = (bf16)b[j]; }
            }
            acw[mt] = v;
        }
        bf16x8 bb[2];
#pragma unroll
        for (int nt = 0; nt < 2; nt++) {
            bf16x8 v;
#pragma unroll
            for (int j = 0; j < 8; j++) v[j] = (bf16)0.f;
            if (lq < 2) {
                int col = n0 + wn * 32 + nt * 16 + lr;
#pragma unroll
                for (int j = 0; j < 8; j++)
                    v[j] = (bf16)bias[(size_t)(lq * 8 + j) * OUT_DIM + col];
            }
            bb[nt] = v;
        }
#pragma unroll
        for (int mt = 0; mt < 4; mt++)
#pragma unroll
            for (int nt = 0; nt < 2; nt++)
                acc[mt][nt] = __builtin_amdgcn_mfma_f32_16x16x32_bf16(
                    bb[nt], acw[mt], acc[mt][nt], 0, 0, 0);
    }

    // epilogue: relu + store. Transposed C/D: lane's 4 acc floats are 4
    // CONSECUTIVE output columns -> one dwordx4 store per (mt,nt).
#pragma unroll
    for (int mt = 0; mt < 4; mt++) {
        int row = m0 + wm * 64 + mt * 16 + lr;
#pragma unroll
        for (int nt = 0; nt < 2; nt++) {
            int col = n0 + wn * 32 + nt * 16 + lq * 4;
            f32x4 v = acc[mt][nt];
#pragma unroll
            for (int r2 = 0; r2 < 4; r2++) v[r2] = v[r2] > 0.f ? v[r2] : 0.f;
            *(f32x4*)(out + (size_t)row * OUT_DIM + col) = v;
        }
    }
}

// ---------------------------------------------------------------------------
// Insurance fallback if ws_size is too small.
// ---------------------------------------------------------------------------
__global__ void fallback_kernel(const float* __restrict__ x, const float* __restrict__ cw,
                                const float* __restrict__ W, const float* __restrict__ bias,
                                float* __restrict__ out) {
    int o = blockIdx.x * 256 + threadIdx.x;
    int b = o >> 10, oc = o & 1023;
    const float* xr = x + (size_t)b * IN_DIM;
    float accv = 0.f;
    for (int n = 0; n < NEXP; n++) {
        const float* wr = W + (size_t)n * IN_DIM * OUT_DIM + oc;
        float z = 0.f;
        for (int i = 0; i < IN_DIM; i++) z += xr[i] * wr[(size_t)i * OUT_DIM];
        accv += cw[(size_t)b * NEXP + n] * (z + bias[n * OUT_DIM + oc]);
    }
    out[o] = accv > 0.f ? accv : 0.f;
}

extern "C" void kernel_launch(void* const* d_in, const int* in_sizes, int n_in,
                              void* d_out, int out_size, void* d_ws, size_t ws_size,
                              hipStream_t stream) {
    const float* x    = (const float*)d_in[0];
    const float* cw   = (const float*)d_in[1];
    const float* W    = (const float*)d_in[2];
    const float* bias = (const float*)d_in[3];
    float* out = (float*)d_out;

    const size_t wt_elems = (size_t)NEXP * IN_DIM * OUT_DIM;   // 32 MB bf16
    const size_t xt_elems = (size_t)BATCH * IN_DIM;            // 8 MB bf16
    if (ws_size < (wt_elems + xt_elems) * sizeof(bf16)) {
        fallback_kernel<<<(BATCH * OUT_DIM) / 256, 256, 0, stream>>>(x, cw, W, bias, out);
        return;
    }
    bf16* wt = (bf16*)d_ws;
    bf16* xt = wt + wt_elems;

    convert_all<<<4096 + 512, 256, 0, stream>>>(x, W, xt, wt);
    moe_gemm<<<dim3(16, 32), 256, 0, stream>>>(cw, bias, xt, wt, out);
}

// Round 13
// 254.424 us; speedup vs baseline: 8.5741x; 8.5741x over previous
//
#include <hip/hip_runtime.h>
#include <hip/hip_bf16.h>
#include <cstdint>

#define BATCH   4096
#define IN_DIM  1024
#define OUT_DIM 1024
#define NEXP    16

typedef __bf16 bf16;
typedef __attribute__((ext_vector_type(8))) __bf16 bf16x8;
typedef __attribute__((ext_vector_type(4))) float  f32x4;

#define AS1 __attribute__((address_space(1)))
#define AS3 __attribute__((address_space(3)))

// ---------------------------------------------------------------------------
// Merged conversion kernel (unchanged — proven clean).
// Blocks [0,4096): weight fp32 -> fragment-ordered bf16 tiles via LDS
//   transpose (coalesced f32x4 row reads).
// Blocks [4096,4608): x fp32 -> 512 pre-tiled swizzled bf16 images.
// ---------------------------------------------------------------------------
__global__ __launch_bounds__(256) void convert_all(
        const float* __restrict__ x, const float* __restrict__ W,
        bf16* __restrict__ xt, bf16* __restrict__ wt) {
    __shared__ float Ls[64][65];       // pad 65: read phase is 2-way (free)
    int t = threadIdx.x;
    int bid = blockIdx.x;
    if (bid < 4096) {
        int nblk = bid >> 8, ne = (bid >> 4) & 15, ks = bid & 15;
        int kb = ne * 1024 + ks * 64;
        int n0 = nblk * 64;
#pragma unroll
        for (int r = 0; r < 4; r++) {
            int idx = r * 256 + t;             // 1024 f32x4 = 64x64 tile
            int row = idx >> 4, c4 = (idx & 15) * 4;
            f32x4 v = *(const f32x4*)(W + (size_t)(kb + row) * OUT_DIM + n0 + c4);
#pragma unroll
            for (int j = 0; j < 4; j++) Ls[row][c4 + j] = v[j];
        }
        __syncthreads();
#pragma unroll
        for (int r = 0; r < 2; r++) {
            int c = r * 256 + t;               // 0..511
            int sub = c >> 6, l = c & 63;
            int lr = l & 15, lq = l >> 4;
            int kk = sub >> 2, wn = (sub >> 1) & 1, nt = sub & 1;
            int krow = kk * 32 + lq * 8;
            int col = wn * 32 + nt * 16 + lr;
            bf16x8 v;
#pragma unroll
            for (int j = 0; j < 8; j++) v[j] = (bf16)Ls[krow + j][col];
            *(bf16x8*)(wt + (size_t)bid * 4096 + c * 8) = v;
        }
    } else {
        int tile = bid - 4096;                 // 512
        int mblk = tile >> 4, ks = tile & 15;
#pragma unroll
        for (int r = 0; r < 4; r++) {
            int q = r * 256 + t;
            int m_loc = q >> 3, sc = q & 7;
            int cc = sc ^ (m_loc & 7);
            const float* src = x + (size_t)(mblk * 128 + m_loc) * IN_DIM + ks * 64 + cc * 8;
            f32x4 a = *(const f32x4*)src;
            f32x4 b = *(const f32x4*)(src + 4);
            bf16x8 v;
#pragma unroll
            for (int j = 0; j < 4; j++) { v[j] = (bf16)a[j]; v[4 + j] = (bf16)b[j]; }
            *(bf16x8*)(xt + (size_t)tile * 8192 + q * 8) = v;
        }
    }
}

// ---------------------------------------------------------------------------
// GEMM R13: barrier-free direct streaming (R11, clean) x 8-wave geometry
// (R8, clean). No LDS operands, no barriers in the K loop, no manual
// pipelining (6 spill incidents prove hipcc punishes it) — latency is
// hidden by THREAD-level parallelism: 512 threads = 16 waves/CU = 4/SIMD,
// wave tile 64m x 16n (bfr[2], acc[4], 8 MFMAs/expert/wave). Per-wave duty
// ~80cyc-MFMA/(200cyc-L2+...) ~ 25-30%; x4 waves/SIMD fills the pipe.
// R11's limiter was the same duty at only 2 waves/SIMD (38% MfmaUtil);
// R8's 4 waves/SIMD were phase-locked by barriers+LDS bursts — this
// combines the fix for both. Loop shape = R11's runtime-ne4/unrolled-e
// (proven non-spilling); all register indices compile-time (rule #20).
// Transposed compute (R5/R7-verified): p = mfma(B,A) -> D=(xW)^T; scale =
// per-lane scalar from LDS cwS (global scales spilled in R10).
// LDS 10.3 KB (cwS only); grid 512 = 2 blocks/CU.
// ---------------------------------------------------------------------------
__global__ __launch_bounds__(512, 2) void moe_gemm(
        const float* __restrict__ cw, const float* __restrict__ bias,
        const bf16* __restrict__ xt, const bf16* __restrict__ wt,
        float* __restrict__ out) {
    int nblk = blockIdx.x;                 // 16; x-major dispatch -> bid%8 =
    int mblk = blockIdx.y;                 // nblk%8 clusters nblk per XCD
    int m0 = mblk * 128, n0 = nblk * 64;
    int t = threadIdx.x;                   // 0..511
    int lane = t & 63, w = t >> 6;         // 8 waves
    int wm = w >> 2, wn = w & 3;           // 2m x 4n
    int lq = lane >> 4, lr = lane & 15;

    __shared__ float cwS[128][20];         // cwS[row_loc][ne], pad 20

    // fill scale table: one f32x4 per thread (512 x 4 = 2048 floats)
    {
        f32x4 v = *(const f32x4*)(cw + (size_t)m0 * NEXP + t * 4);
        *(f32x4*)&cwS[t >> 2][(t & 3) * 4] = v;
    }
    __syncthreads();                       // the ONLY barrier

    const f32x4 fz = {0.f, 0.f, 0.f, 0.f};
    f32x4 acc[4];
#pragma unroll
    for (int mt = 0; mt < 4; mt++) acc[mt] = fz;

    int swz = lr & 7;
    int mrow[4];
#pragma unroll
    for (int mt = 0; mt < 4; mt++) mrow[mt] = (wm * 64 + mt * 16 + lr) * 64;

    const bf16* abase = xt + (size_t)(mblk * 16) * 8192;
    // per-wave B fragment base: chunk offset (kk*4 + wn)*512 + lane*8
    const bf16* bbase = wt + (size_t)nblk * (16 * 16 * 4096) + lane * 8;
    const float* cwrow0 = &cwS[wm * 64 + lr][0];

#pragma unroll 1
    for (int ks = 0; ks < 16; ks++) {
        // A fragments -> registers straight from the xt image (L2-hot),
        // reused across all 16 experts
        bf16x8 af[4][2];
        const bf16* asrc = abase + (size_t)ks * 8192;
#pragma unroll
        for (int kk = 0; kk < 2; kk++)
#pragma unroll
            for (int mt = 0; mt < 4; mt++)
                af[mt][kk] = *(const bf16x8*)
                    (asrc + mrow[mt] + ((kk * 4 + lq) ^ swz) * 8);

#pragma unroll 1
        for (int ne4 = 0; ne4 < 4; ne4++) {    // runtime: caps load hoisting
            // scales for this group's 4 experts (one b128 per mt, LDS)
            f32x4 sg[4];
#pragma unroll
            for (int mt = 0; mt < 4; mt++)
                sg[mt] = *(const f32x4*)(cwrow0 + mt * (16 * 20) + ne4 * 4);
#pragma unroll
            for (int e = 0; e < 4; e++) {
                const bf16* btile = bbase + (size_t)((ne4 * 4 + e) * 16 + ks) * 4096;
                // B fragments straight from fragment-ordered wt (coalesced
                // 1KB wave-loads; sub = kk*4 + wn, R8-verified vs wt image)
                bf16x8 bfr[2];
#pragma unroll
                for (int kk = 0; kk < 2; kk++)
                    bfr[kk] = *(const bf16x8*)(btile + (kk * 4 + wn) * 512);
                // MFMA (swapped operands -> transposed D) + scalar fold
#pragma unroll
                for (int mt = 0; mt < 4; mt++) {
                    float sv = sg[mt][e];          // compile-time extract
                    f32x4 p = __builtin_amdgcn_mfma_f32_16x16x32_bf16(
                        bfr[0], af[mt][0], fz, 0, 0, 0);
                    p = __builtin_amdgcn_mfma_f32_16x16x32_bf16(
                        bfr[1], af[mt][1], p, 0, 0, 0);
                    acc[mt] += sv * p;
                }
            }
        }
    }

    // ---- bias: one MFMA k-step (k = ne), swapped operands like the body ----
    {
        bf16x8 acw[4];
#pragma unroll
        for (int mt = 0; mt < 4; mt++) {
            bf16x8 v;
#pragma unroll
            for (int j = 0; j < 8; j++) v[j] = (bf16)0.f;
            if (lq < 2) {                  // k = lq*8+j in 0..15 real, else 0
                int row = m0 + wm * 64 + mt * 16 + lr;
                f32x4 a = *(const f32x4*)(cw + (size_t)row * NEXP + lq * 8);
                f32x4 b = *(const f32x4*)(cw + (size_t)row * NEXP + lq * 8 + 4);
#pragma unroll
                for (int j = 0; j < 4; j++) { v[j] = (bf16)a[j]; v[4 + j] = (bf16)b[j]; }
            }
            acw[mt] = v;
        }
        bf16x8 bb;
        {
            bf16x8 v;
#pragma unroll
            for (int j = 0; j < 8; j++) v[j] = (bf16)0.f;
            if (lq < 2) {
                int col = n0 + wn * 16 + lr;
#pragma unroll
                for (int j = 0; j < 8; j++)
                    v[j] = (bf16)bias[(size_t)(lq * 8 + j) * OUT_DIM + col];
            }
            bb = v;
        }
#pragma unroll
        for (int mt = 0; mt < 4; mt++)
            acc[mt] = __builtin_amdgcn_mfma_f32_16x16x32_bf16(
                bb, acw[mt], acc[mt], 0, 0, 0);
    }

    // epilogue: relu + store. Transposed C/D: lane's 4 acc floats are 4
    // CONSECUTIVE output columns -> one dwordx4 store per mt.
#pragma unroll
    for (int mt = 0; mt < 4; mt++) {
        int row = m0 + wm * 64 + mt * 16 + lr;
        int col = n0 + wn * 16 + lq * 4;
        f32x4 v = acc[mt];
#pragma unroll
        for (int r2 = 0; r2 < 4; r2++) v[r2] = v[r2] > 0.f ? v[r2] : 0.f;
        *(f32x4*)(out + (size_t)row * OUT_DIM + col) = v;
    }
}

// ---------------------------------------------------------------------------
// Insurance fallback if ws_size is too small.
// ---------------------------------------------------------------------------
__global__ void fallback_kernel(const float* __restrict__ x, const float* __restrict__ cw,
                                const float* __restrict__ W, const float* __restrict__ bias,
                                float* __restrict__ out) {
    int o = blockIdx.x * 256 + threadIdx.x;
    int b = o >> 10, oc = o & 1023;
    const float* xr = x + (size_t)b * IN_DIM;
    float accv = 0.f;
    for (int n = 0; n < NEXP; n++) {
        const float* wr = W + (size_t)n * IN_DIM * OUT_DIM + oc;
        float z = 0.f;
        for (int i = 0; i < IN_DIM; i++) z += xr[i] * wr[(size_t)i * OUT_DIM];
        accv += cw[(size_t)b * NEXP + n] * (z + bias[n * OUT_DIM + oc]);
    }
    out[o] = accv > 0.f ? accv : 0.f;
}

extern "C" void kernel_launch(void* const* d_in, const int* in_sizes, int n_in,
                              void* d_out, int out_size, void* d_ws, size_t ws_size,
                              hipStream_t stream) {
    const float* x    = (const float*)d_in[0];
    const float* cw   = (const float*)d_in[1];
    const float* W    = (const float*)d_in[2];
    const float* bias = (const float*)d_in[3];
    float* out = (float*)d_out;

    const size_t wt_elems = (size_t)NEXP * IN_DIM * OUT_DIM;   // 32 MB bf16
    const size_t xt_elems = (size_t)BATCH * IN_DIM;            // 8 MB bf16
    if (ws_size < (wt_elems + xt_elems) * sizeof(bf16)) {
        fallback_kernel<<<(BATCH * OUT_DIM) / 256, 256, 0, stream>>>(x, cw, W, bias, out);
        return;
    }
    bf16* wt = (bf16*)d_ws;
    bf16* xt = wt + wt_elems;

    convert_all<<<4096 + 512, 256, 0, stream>>>(x, W, xt, wt);
    moe_gemm<<<dim3(16, 32), 512, 0, stream>>>(cw, bias, xt, wt, out);
}

// Round 14
// 240.718 us; speedup vs baseline: 9.0623x; 1.0569x over previous
//
#include <hip/hip_runtime.h>
#include <hip/hip_bf16.h>
#include <cstdint>

#define BATCH   4096
#define IN_DIM  1024
#define OUT_DIM 1024
#define NEXP    16

typedef __bf16 bf16;
typedef __attribute__((ext_vector_type(8))) __bf16 bf16x8;
typedef __attribute__((ext_vector_type(4))) float  f32x4;

#define AS1 __attribute__((address_space(1)))
#define AS3 __attribute__((address_space(3)))

__device__ __forceinline__ void gld_lds16(const bf16* g, bf16* l) {
    __builtin_amdgcn_global_load_lds((const AS1 void*)g, (AS3 void*)l, 16, 0, 0);
}

// ---------------------------------------------------------------------------
// Merged conversion kernel (proven clean).
// Blocks [0,4096): weight fp32 -> fragment-ordered bf16 tiles via LDS
//   transpose (coalesced f32x4 row reads).
// Blocks [4096,4608): x fp32 -> 512 pre-tiled swizzled bf16 images.
// ---------------------------------------------------------------------------
__global__ __launch_bounds__(256) void convert_all(
        const float* __restrict__ x, const float* __restrict__ W,
        bf16* __restrict__ xt, bf16* __restrict__ wt) {
    __shared__ float Ls[64][65];       // pad 65: read phase is 2-way (free)
    int t = threadIdx.x;
    int bid = blockIdx.x;
    if (bid < 4096) {
        int nblk = bid >> 8, ne = (bid >> 4) & 15, ks = bid & 15;
        int kb = ne * 1024 + ks * 64;
        int n0 = nblk * 64;
#pragma unroll
        for (int r = 0; r < 4; r++) {
            int idx = r * 256 + t;             // 1024 f32x4 = 64x64 tile
            int row = idx >> 4, c4 = (idx & 15) * 4;
            f32x4 v = *(const f32x4*)(W + (size_t)(kb + row) * OUT_DIM + n0 + c4);
#pragma unroll
            for (int j = 0; j < 4; j++) Ls[row][c4 + j] = v[j];
        }
        __syncthreads();
#pragma unroll
        for (int r = 0; r < 2; r++) {
            int c = r * 256 + t;               // 0..511
            int sub = c >> 6, l = c & 63;
            int lr = l & 15, lq = l >> 4;
            int kk = sub >> 2, wn = (sub >> 1) & 1, nt = sub & 1;
            int krow = kk * 32 + lq * 8;
            int col = wn * 32 + nt * 16 + lr;
            bf16x8 v;
#pragma unroll
            for (int j = 0; j < 8; j++) v[j] = (bf16)Ls[krow + j][col];
            *(bf16x8*)(wt + (size_t)bid * 4096 + c * 8) = v;
        }
    } else {
        int tile = bid - 4096;                 // 512
        int mblk = tile >> 4, ks = tile & 15;
#pragma unroll
        for (int r = 0; r < 4; r++) {
            int q = r * 256 + t;
            int m_loc = q >> 3, sc = q & 7;
            int cc = sc ^ (m_loc & 7);
            const float* src = x + (size_t)(mblk * 128 + m_loc) * IN_DIM + ks * 64 + cc * 8;
            f32x4 a = *(const f32x4*)src;
            f32x4 b = *(const f32x4*)(src + 4);
            bf16x8 v;
#pragma unroll
            for (int j = 0; j < 4; j++) { v[j] = (bf16)a[j]; v[4 + j] = (bf16)b[j]; }
            *(bf16x8*)(xt + (size_t)tile * 8192 + q * 8) = v;
        }
    }
}

// ---------------------------------------------------------------------------
// GEMM — the R7 champion, verbatim. Transposed compute (verified):
// p = mfma(B_frag, A_frag, ·) gives D = (x·W)^T; D col (lane&15) = batch
// row, so the combine scale cw[b][ne] is a per-lane scalar. Scales live in
// LDS (cwS[128][20], pad 20 -> aligned b128), fetched as a 4-expert group
// sg[mt] = ds_read_b128 at each ne%4==0 (16 VGPRs live for 4 ne's).
// Loop/barrier shape: 4 B-buffers, prefetch pair {ne+2,ne+3} before
// computing pair {ne,ne+1}, __syncthreads per pair, no inline asm,
// compile-time buffer indices under full unroll.
// Evidence closing the session: five clean structures ({LDS vs L2-direct
// operands} x {barriers vs none} x {2 vs 4 waves/SIMD}) all land at
// 145-155us / MfmaUtil 38-42%; every deeper-scheduling attempt (6) spills
// to scratch on this compiler. The binding constraint is the per-expert
// MFMA->VALU scale-fold round-trip, which is algorithmically required.
// Block 128m x 64n, 4 waves (2x2), wave tile 64x32, mfma 16x16x32 bf16.
// LDS 58 KB; grid 512 = 2 blocks/CU (grid-limited).
// ---------------------------------------------------------------------------
__global__ __launch_bounds__(256, 2) void moe_gemm(
        const float* __restrict__ cw, const float* __restrict__ bias,
        const bf16* __restrict__ xt, const bf16* __restrict__ wt,
        float* __restrict__ out) {
    int nblk = blockIdx.x;                 // 16 -> bid%8 clusters nblk per XCD
    int mblk = blockIdx.y;                 // 32
    int m0 = mblk * 128, n0 = nblk * 64;
    int t = threadIdx.x;
    int lane = t & 63, w = t >> 6;
    int wm = w >> 1, wn = w & 1;
    int lq = lane >> 4, lr = lane & 15;

    __shared__ bf16 As[128 * 64];          // 16 KB swizzled A image
    __shared__ bf16 Bs[4][64 * 64];        // 4 x 8 KB fragment-ordered B tiles
    __shared__ float cwS[128][20];         // cwS[row_loc][ne], pad 20

    // fill scale table: coalesced f32x4 global loads, aligned b128 LDS writes
#pragma unroll
    for (int r = 0; r < 2; r++) {
        int q = r * 256 + t;               // 512 f32x4 = 2048 floats
        f32x4 v = *(const f32x4*)(cw + (size_t)m0 * NEXP + q * 4);
        *(f32x4*)&cwS[q >> 2][(q & 3) * 4] = v;
    }

    const f32x4 fz = {0.f, 0.f, 0.f, 0.f};
    f32x4 acc[4][2];
#pragma unroll
    for (int mt = 0; mt < 4; mt++)
#pragma unroll
        for (int nt = 0; nt < 2; nt++) acc[mt][nt] = fz;

    int swz = lr & 7;
    int mrow[4];
#pragma unroll
    for (int mt = 0; mt < 4; mt++) mrow[mt] = (wm * 64 + mt * 16 + lr) * 64;

    const bf16* abase = xt + (size_t)(mblk * 16) * 8192;
    const bf16* bbase = wt + (size_t)nblk * (16 * 16 * 4096);

#pragma unroll 1
    for (int ks = 0; ks < 16; ks++) {
        // stage A tile (16 KB) + B tiles for ne=0,1; one drain barrier
        // (the ks=0 barrier also publishes cwS)
        const bf16* asrc = abase + (size_t)ks * 8192 + t * 8;
#pragma unroll
        for (int r = 0; r < 4; r++) gld_lds16(asrc + r * 2048, &As[r * 2048 + t * 8]);
        const bf16* b0 = bbase + (size_t)ks * 4096 + t * 8;          // ne = 0
        gld_lds16(b0,        &Bs[0][t * 8]);
        gld_lds16(b0 + 2048, &Bs[0][2048 + t * 8]);
        const bf16* b1 = bbase + (size_t)(16 + ks) * 4096 + t * 8;   // ne = 1
        gld_lds16(b1,        &Bs[1][t * 8]);
        gld_lds16(b1 + 2048, &Bs[1][2048 + t * 8]);
        __syncthreads();

        // A fragments -> registers, reused across all 16 experts
        bf16x8 af[4][2];
#pragma unroll
        for (int kk = 0; kk < 2; kk++)
#pragma unroll
            for (int mt = 0; mt < 4; mt++)
                af[mt][kk] = *(const bf16x8*)&As[mrow[mt] + ((kk * 4 + lq) ^ swz) * 8];

        f32x4 sg[4];                       // 4-expert scale group (16 VGPRs)
#pragma unroll
        for (int ne = 0; ne < 16; ne++) {
            if ((ne & 3) == 0) {           // refresh scales for ne..ne+3
#pragma unroll
                for (int mt = 0; mt < 4; mt++)
                    sg[mt] = *(const f32x4*)&cwS[wm * 64 + mt * 16 + lr][ne];
            }
            if ((ne & 1) == 0 && ne < 14) {    // prefetch pair {ne+2, ne+3}
                const bf16* bn2 = bbase + (size_t)((ne + 2) * 16 + ks) * 4096 + t * 8;
                bf16* bd2 = &Bs[(ne + 2) & 3][t * 8];
                gld_lds16(bn2,        bd2);
                gld_lds16(bn2 + 2048, bd2 + 2048);
                const bf16* bn3 = bbase + (size_t)((ne + 3) * 16 + ks) * 4096 + t * 8;
                bf16* bd3 = &Bs[(ne + 3) & 3][t * 8];
                gld_lds16(bn3,        bd3);
                gld_lds16(bn3 + 2048, bd3 + 2048);
            }
            // B fragments (linear, conflict-free)
            bf16x8 bfr[2][2];
#pragma unroll
            for (int kk = 0; kk < 2; kk++)
#pragma unroll
                for (int nt = 0; nt < 2; nt++)
                    bfr[kk][nt] = *(const bf16x8*)
                        &Bs[ne & 3][((kk * 2 + wn) * 2 + nt) * 512 + lane * 8];
            // MFMA (swapped operands -> transposed D) + scalar-scale fold
#pragma unroll
            for (int mt = 0; mt < 4; mt++) {
                float sv = sg[mt][ne & 3];          // compile-time extract
#pragma unroll
                for (int nt = 0; nt < 2; nt++) {
                    f32x4 p = __builtin_amdgcn_mfma_f32_16x16x32_bf16(
                        bfr[0][nt], af[mt][0], fz, 0, 0, 0);
                    p = __builtin_amdgcn_mfma_f32_16x16x32_bf16(
                        bfr[1][nt], af[mt][1], p, 0, 0, 0);
                    acc[mt][nt] += sv * p;
                }
            }
            if (ne & 1) __syncthreads();       // barrier per expert pair
        }
    }

    // ---- bias: one MFMA k-step (k = ne), swapped operands like the body ----
    {
        bf16x8 acw[4];
#pragma unroll
        for (int mt = 0; mt < 4; mt++) {
            bf16x8 v;
#pragma unroll
            for (int j = 0; j < 8; j++) v[j] = (bf16)0.f;
            if (lq < 2) {                  // k = lq*8+j in 0..15 real, else 0
                int row = m0 + wm * 64 + mt * 16 + lr;
                f32x4 a = *(const f32x4*)(cw + (size_t)row * NEXP + lq * 8);
                f32x4 b = *(const f32x4*)(cw + (size_t)row * NEXP + lq * 8 + 4);
#pragma unroll
                for (int j = 0; j < 4; j++) { v[j] = (bf16)a[j]; v[4 + j] = (bf16)b[j]; }
            }
            acw[mt] = v;
        }
        bf16x8 bb[2];
#pragma unroll
        for (int nt = 0; nt < 2; nt++) {
            bf16x8 v;
#pragma unroll
            for (int j = 0; j < 8; j++) v[j] = (bf16)0.f;
            if (lq < 2) {
                int col = n0 + wn * 32 + nt * 16 + lr;
#pragma unroll
                for (int j = 0; j < 8; j++)
                    v[j] = (bf16)bias[(size_t)(lq * 8 + j) * OUT_DIM + col];
            }
            bb[nt] = v;
        }
#pragma unroll
        for (int mt = 0; mt < 4; mt++)
#pragma unroll
            for (int nt = 0; nt < 2; nt++)
                acc[mt][nt] = __builtin_amdgcn_mfma_f32_16x16x32_bf16(
                    bb[nt], acw[mt], acc[mt][nt], 0, 0, 0);
    }

    // epilogue: relu + store. Transposed C/D: lane's 4 acc floats are 4
    // CONSECUTIVE output columns -> one dwordx4 store per (mt,nt).
    //   row = m0 + wm*64 + mt*16 + lr;  col = n0 + wn*32 + nt*16 + lq*4 + r2
#pragma unroll
    for (int mt = 0; mt < 4; mt++) {
        int row = m0 + wm * 64 + mt * 16 + lr;
#pragma unroll
        for (int nt = 0; nt < 2; nt++) {
            int col = n0 + wn * 32 + nt * 16 + lq * 4;
            f32x4 v = acc[mt][nt];
#pragma unroll
            for (int r2 = 0; r2 < 4; r2++) v[r2] = v[r2] > 0.f ? v[r2] : 0.f;
            *(f32x4*)(out + (size_t)row * OUT_DIM + col) = v;
        }
    }
}

// ---------------------------------------------------------------------------
// Insurance fallback if ws_size is too small.
// ---------------------------------------------------------------------------
__global__ void fallback_kernel(const float* __restrict__ x, const float* __restrict__ cw,
                                const float* __restrict__ W, const float* __restrict__ bias,
                                float* __restrict__ out) {
    int o = blockIdx.x * 256 + threadIdx.x;
    int b = o >> 10, oc = o & 1023;
    const float* xr = x + (size_t)b * IN_DIM;
    float accv = 0.f;
    for (int n = 0; n < NEXP; n++) {
        const float* wr = W + (size_t)n * IN_DIM * OUT_DIM + oc;
        float z = 0.f;
        for (int i = 0; i < IN_DIM; i++) z += xr[i] * wr[(size_t)i * OUT_DIM];
        accv += cw[(size_t)b * NEXP + n] * (z + bias[n * OUT_DIM + oc]);
    }
    out[o] = accv > 0.f ? accv : 0.f;
}

extern "C" void kernel_launch(void* const* d_in, const int* in_sizes, int n_in,
                              void* d_out, int out_size, void* d_ws, size_t ws_size,
                              hipStream_t stream) {
    const float* x    = (const float*)d_in[0];
    const float* cw   = (const float*)d_in[1];
    const float* W    = (const float*)d_in[2];
    const float* bias = (const float*)d_in[3];
    float* out = (float*)d_out;

    const size_t wt_elems = (size_t)NEXP * IN_DIM * OUT_DIM;   // 32 MB bf16
    const size_t xt_elems = (size_t)BATCH * IN_DIM;            // 8 MB bf16
    if (ws_size < (wt_elems + xt_elems) * sizeof(bf16)) {
        fallback_kernel<<<(BATCH * OUT_DIM) / 256, 256, 0, stream>>>(x, cw, W, bias, out);
        return;
    }
    bf16* wt = (bf16*)d_ws;
    bf16* xt = wt + wt_elems;

    convert_all<<<4096 + 512, 256, 0, stream>>>(x, W, xt, wt);
    moe_gemm<<<dim3(16, 32), 256, 0, stream>>>(cw, bias, xt, wt, out);
}